// Round 7
// baseline (203.434 us; speedup 1.0000x reference)
//
#include <hip/hip_runtime.h>
#include <math.h>

// BasicBlockA: masked conv (L*C) + bias + ELU -> grouped masked conv -> mean over L + residual.
// Mask: kernel row ky=2 always zero; row ky=1 keeps kx=0 always and kx=1 iff j<=i (42 live taps).
// R7 = R4 body (best: 97us, VGPR 56, no spill) + latent loop split across 2 blocks
// (grid 2048 -> 5 blocks/CU resident vs 4, backfill smooths tail) accumulating into a
// pre-zeroed d_out via fp32 global atomicAdd. Residual added by half 0 only.
// R6 lesson: ping-pong hs (45KB LDS) cut occupancy and regressed; conflicts 1.8e7 are
// inherent b128 wide-op serialization, not addressing bugs.

namespace {
constexpr int NC = 3, NH = 128, NW = 128, NL = 16;
constexpr int TILE = 32;
constexpr int XR = 34, XC = 40;  // x tile: rows (oy0-2 .. oy0+31), 40-col stride, 3ch interleaved
constexpr int HR = 33, HC = 36;  // h tile: rows (oy0-1 .. oy0+31), 36-col stride, 3ch interleaved
constexpr int WPL = 54;          // packed weights per latent: [i][j][ky<2][kx<3]
}

__device__ __forceinline__ float softplusf(float v) {
    return v > 20.f ? v : log1pf(expf(v));
}

// Build masked weights into d_ws: wb[0..863] = w1 packed, wb[864..1727] = w2 packed.
__global__ void prep_weights(const float* __restrict__ w1, const float* __restrict__ c1,
                             const float* __restrict__ w2, const float* __restrict__ c2,
                             float* __restrict__ wb) {
    int e = blockIdx.x * blockDim.x + threadIdx.x;
    if (e >= NL * NC * NC * 2 * 3) return;
    int kx = e % 3;
    int ky = (e / 3) % 2;
    int j  = (e / 6) % 3;
    int i  = (e / 18) % 3;
    int l  = e / WPL;
    int g = l * 81 + i * 27 + j * 9 + ky * 3 + kx;  // [L,C,C,3,3] global index
    bool used   = (ky == 0) || (kx == 0) || (kx == 1 && j <= i);
    bool center = (i == j) && (ky == 1) && (kx == 1);
    wb[e]       = used ? (center ? softplusf(c1[g]) : w1[g]) : 0.f;
    wb[864 + e] = used ? (center ? softplusf(c2[g]) : w2[g]) : 0.f;
}

__device__ __forceinline__ float eluf(float v) {
    float e = __expf(v) - 1.f;
    return v > 0.f ? v : e;
}

__global__ __launch_bounds__(256, 4) void fused_block(
    const float* __restrict__ x, const float* __restrict__ bias1,
    const float* __restrict__ res, const float* __restrict__ wb,
    float* __restrict__ out)
{
    __shared__ alignas(16) float xs[XR * XC * 3];
    __shared__ alignas(16) float hs[HR * HC * 3];

    const int tid  = threadIdx.x;
    const int b    = blockIdx.z;
    const int oy0  = blockIdx.y * TILE;
    const int half = blockIdx.x & 1;            // latent half: 0 -> l 0..7, 1 -> l 8..15
    const int ox0  = (blockIdx.x >> 1) * TILE;

    // ---- load x tile: planar (coalesced) global reads, channel-interleaved LDS store ----
    const float* xb = x + b * NC * NH * NW;
    for (int idx = tid; idx < XR * XC * 3; idx += 256) {
        int lx = idx % XC;
        int ly = (idx / XC) % XR;
        int c  = idx / (XC * XR);
        int gy = oy0 - 2 + ly, gx = ox0 - 2 + lx;
        float v = 0.f;
        if (gy >= 0 && gy < NH && gx >= 0 && gx < NW)
            v = xb[c * NH * NW + gy * NW + gx];
        xs[(ly * XC + lx) * 3 + c] = v;
    }

    // ---- stage-1 chunk map: A = 32 rows x 8 chunks; B = 41 edge chunks on wave 0 ----
    const int rA = tid >> 3;           // h row 0..31
    const int cA = (tid & 7) * 4;      // h col 0..28 step 4
    const bool hasB = (tid < 41);      // wave 0 only (other waves skip via execz)
    const int rB = (tid < 33) ? tid : 32;
    const int cB = (tid < 33) ? 32 : (tid - 33) * 4;

    // boundary masks as float 0/1, computed once
    float4 mA, mB;
    {
        int gyA = oy0 - 1 + rA;
        bool ra = (gyA >= 0 && gyA < NH);
        int gyB = oy0 - 1 + rB;
        bool rb = (gyB >= 0 && gyB < NH);
        int gxA = ox0 - 1 + cA, gxB = ox0 - 1 + cB;
        mA.x = (ra && gxA + 0 >= 0 && gxA + 0 < NW) ? 1.f : 0.f;
        mA.y = (ra && gxA + 1 >= 0 && gxA + 1 < NW) ? 1.f : 0.f;
        mA.z = (ra && gxA + 2 >= 0 && gxA + 2 < NW) ? 1.f : 0.f;
        mA.w = (ra && gxA + 3 >= 0 && gxA + 3 < NW) ? 1.f : 0.f;
        mB.x = (rb && gxB + 0 >= 0 && gxB + 0 < NW) ? 1.f : 0.f;
        mB.y = (rb && gxB + 1 >= 0 && gxB + 1 < NW) ? 1.f : 0.f;
        mB.z = (rb && gxB + 2 >= 0 && gxB + 2 < NW) ? 1.f : 0.f;
        mB.w = (rb && gxB + 3 >= 0 && gxB + 3 < NW) ? 1.f : 0.f;
    }

    const int ty = tid >> 3;       // output row within tile (0..31)
    const int tx = (tid & 7) * 4;  // output col, 1x4 chunk per thread

    // hoisted LDS addresses (all 16B-aligned: 48B chunk stride, rows mult of 16B)
    const float* xA0 = &xs[(rA * XC + cA) * 3];
    const float* xA1 = &xs[((rA + 1) * XC + cA) * 3];
    float*       hA  = &hs[(rA * HC + cA) * 3];
    const float* xB0 = &xs[(rB * XC + cB) * 3];
    const float* xB1 = &xs[((rB + 1) * XC + cB) * 3];
    float*       hB  = &hs[(rB * HC + cB) * 3];
    const float* h20 = &hs[(ty * HC + tx) * 3];
    const float* h21 = &hs[((ty + 1) * HC + tx) * 3];

    float acc[3][4] = {{0.f}};

    const int l0 = half * (NL / 2);

    #pragma unroll 1
    for (int l = l0; l < l0 + NL / 2; ++l) {
        // stage-1 weights (uniform index -> scalar loads); only live taps read
        float w1r[3][3][2][3];
        #pragma unroll
        for (int i = 0; i < 3; ++i)
        #pragma unroll
        for (int j = 0; j < 3; ++j)
        #pragma unroll
        for (int ky = 0; ky < 2; ++ky)
        #pragma unroll
        for (int kx = 0; kx < 3; ++kx)
            if (ky == 0 || kx == 0 || (kx == 1 && j <= i))
                w1r[i][j][ky][kx] = wb[l * WPL + i * 18 + j * 6 + ky * 3 + kx];
        float br[3];
        #pragma unroll
        for (int i = 0; i < 3; ++i) br[i] = bias1[l * 3 + i];

        __syncthreads();  // prev latent's stage-2 reads done -> hs writable; xs ready at l==l0

        // ---- stage 1, chunk A (all threads) ----
        {
            float4 v0 = ((const float4*)xA0)[0], v1 = ((const float4*)xA0)[1];
            float4 v2 = ((const float4*)xA0)[2], v3 = ((const float4*)xA0)[3];
            float2 v4 = ((const float2*)xA0)[8];
            float4 u0 = ((const float4*)xA1)[0], u1 = ((const float4*)xA1)[1];
            float4 u2 = ((const float4*)xA1)[2], u3 = ((const float4*)xA1)[3];
            float x0[18] = {v0.x,v0.y,v0.z,v0.w,v1.x,v1.y,v1.z,v1.w,
                            v2.x,v2.y,v2.z,v2.w,v3.x,v3.y,v3.z,v3.w,v4.x,v4.y};
            float x1[16] = {u0.x,u0.y,u0.z,u0.w,u1.x,u1.y,u1.z,u1.w,
                            u2.x,u2.y,u2.z,u2.w,u3.x,u3.y,u3.z,u3.w};
            float pre[3][4];
            #pragma unroll
            for (int i = 0; i < 3; ++i)
                #pragma unroll
                for (int p = 0; p < 4; ++p) pre[i][p] = br[i];
            #pragma unroll
            for (int i = 0; i < 3; ++i)
            #pragma unroll
            for (int j = 0; j < 3; ++j)
            #pragma unroll
            for (int kx = 0; kx < 3; ++kx) {
                float w0 = w1r[i][j][0][kx];
                #pragma unroll
                for (int p = 0; p < 4; ++p)
                    pre[i][p] += w0 * x0[(kx + p) * 3 + j];
                if (kx == 0 || (kx == 1 && j <= i)) {
                    float w1v = w1r[i][j][1][kx];
                    #pragma unroll
                    for (int p = 0; p < 4; ++p)
                        pre[i][p] += w1v * x1[(kx + p) * 3 + j];
                }
            }
            float m[4] = {mA.x, mA.y, mA.z, mA.w};
            float hv[12];
            #pragma unroll
            for (int p = 0; p < 4; ++p)
                #pragma unroll
                for (int i = 0; i < 3; ++i)
                    hv[p * 3 + i] = eluf(pre[i][p]) * m[p];
            ((float4*)hA)[0] = make_float4(hv[0], hv[1], hv[2],  hv[3]);
            ((float4*)hA)[1] = make_float4(hv[4], hv[5], hv[6],  hv[7]);
            ((float4*)hA)[2] = make_float4(hv[8], hv[9], hv[10], hv[11]);
        }
        // ---- stage 1, chunk B: tid<41, wave 0 only ----
        if (hasB) {
            float4 v0 = ((const float4*)xB0)[0], v1 = ((const float4*)xB0)[1];
            float4 v2 = ((const float4*)xB0)[2], v3 = ((const float4*)xB0)[3];
            float2 v4 = ((const float2*)xB0)[8];
            float4 u0 = ((const float4*)xB1)[0], u1 = ((const float4*)xB1)[1];
            float4 u2 = ((const float4*)xB1)[2], u3 = ((const float4*)xB1)[3];
            float x0[18] = {v0.x,v0.y,v0.z,v0.w,v1.x,v1.y,v1.z,v1.w,
                            v2.x,v2.y,v2.z,v2.w,v3.x,v3.y,v3.z,v3.w,v4.x,v4.y};
            float x1[16] = {u0.x,u0.y,u0.z,u0.w,u1.x,u1.y,u1.z,u1.w,
                            u2.x,u2.y,u2.z,u2.w,u3.x,u3.y,u3.z,u3.w};
            float pre[3][4];
            #pragma unroll
            for (int i = 0; i < 3; ++i)
                #pragma unroll
                for (int p = 0; p < 4; ++p) pre[i][p] = br[i];
            #pragma unroll
            for (int i = 0; i < 3; ++i)
            #pragma unroll
            for (int j = 0; j < 3; ++j)
            #pragma unroll
            for (int kx = 0; kx < 3; ++kx) {
                float w0 = w1r[i][j][0][kx];
                #pragma unroll
                for (int p = 0; p < 4; ++p)
                    pre[i][p] += w0 * x0[(kx + p) * 3 + j];
                if (kx == 0 || (kx == 1 && j <= i)) {
                    float w1v = w1r[i][j][1][kx];
                    #pragma unroll
                    for (int p = 0; p < 4; ++p)
                        pre[i][p] += w1v * x1[(kx + p) * 3 + j];
                }
            }
            float m[4] = {mB.x, mB.y, mB.z, mB.w};
            float hv[12];
            #pragma unroll
            for (int p = 0; p < 4; ++p)
                #pragma unroll
                for (int i = 0; i < 3; ++i)
                    hv[p * 3 + i] = eluf(pre[i][p]) * m[p];
            ((float4*)hB)[0] = make_float4(hv[0], hv[1], hv[2],  hv[3]);
            ((float4*)hB)[1] = make_float4(hv[4], hv[5], hv[6],  hv[7]);
            ((float4*)hB)[2] = make_float4(hv[8], hv[9], hv[10], hv[11]);
        }

        // stage-2 weights: scalar loads issued before the barrier
        float w2r[3][3][2][3];
        #pragma unroll
        for (int i = 0; i < 3; ++i)
        #pragma unroll
        for (int j = 0; j < 3; ++j)
        #pragma unroll
        for (int ky = 0; ky < 2; ++ky)
        #pragma unroll
        for (int kx = 0; kx < 3; ++kx)
            if (ky == 0 || kx == 0 || (kx == 1 && j <= i))
                w2r[i][j][ky][kx] = wb[864 + l * WPL + i * 18 + j * 6 + ky * 3 + kx];

        __syncthreads();  // hs ready

        // ---- stage 2: acc += conv(h, w2[l]) at this thread's 1x4 outputs ----
        {
            float4 v0 = ((const float4*)h20)[0], v1 = ((const float4*)h20)[1];
            float4 v2 = ((const float4*)h20)[2], v3 = ((const float4*)h20)[3];
            float2 v4 = ((const float2*)h20)[8];
            float4 u0 = ((const float4*)h21)[0], u1 = ((const float4*)h21)[1];
            float4 u2 = ((const float4*)h21)[2], u3 = ((const float4*)h21)[3];
            float h0[18] = {v0.x,v0.y,v0.z,v0.w,v1.x,v1.y,v1.z,v1.w,
                            v2.x,v2.y,v2.z,v2.w,v3.x,v3.y,v3.z,v3.w,v4.x,v4.y};
            float h1[16] = {u0.x,u0.y,u0.z,u0.w,u1.x,u1.y,u1.z,u1.w,
                            u2.x,u2.y,u2.z,u2.w,u3.x,u3.y,u3.z,u3.w};
            #pragma unroll
            for (int i = 0; i < 3; ++i)
            #pragma unroll
            for (int j = 0; j < 3; ++j)
            #pragma unroll
            for (int kx = 0; kx < 3; ++kx) {
                float w0 = w2r[i][j][0][kx];
                #pragma unroll
                for (int p = 0; p < 4; ++p)
                    acc[i][p] += w0 * h0[(kx + p) * 3 + j];
                if (kx == 0 || (kx == 1 && j <= i)) {
                    float w1v = w2r[i][j][1][kx];
                    #pragma unroll
                    for (int p = 0; p < 4; ++p)
                        acc[i][p] += w1v * h1[(kx + p) * 3 + j];
                }
            }
        }
    }

    // ---- epilogue: atomic partial-sum; residual added by half 0 only ----
    float rv = res[0];
    float rg = (half == 0 && rv > 0.f) ? rv : 0.f;
    const int gy = oy0 + ty;
    float* ob = out + b * NC * NH * NW;
    #pragma unroll
    for (int i = 0; i < 3; ++i) {
        float* op = ob + i * NH * NW + gy * NW + ox0 + tx;
        #pragma unroll
        for (int p = 0; p < 4; ++p) {
            float v = acc[i][p] * (1.f / 16.f)
                    + rg * xs[((ty + 2) * XC + tx + 2 + p) * 3 + i];
            atomicAdd(op + p, v);
        }
    }
}

extern "C" void kernel_launch(void* const* d_in, const int* in_sizes, int n_in,
                              void* d_out, int out_size, void* d_ws, size_t ws_size,
                              hipStream_t stream) {
    (void)in_sizes; (void)n_in; (void)ws_size;
    const float* x   = (const float*)d_in[0];
    const float* w1  = (const float*)d_in[1];
    const float* c1  = (const float*)d_in[2];
    const float* b1  = (const float*)d_in[3];
    const float* w2  = (const float*)d_in[4];
    const float* c2  = (const float*)d_in[5];
    const float* res = (const float*)d_in[6];
    float* out = (float*)d_out;
    float* wb  = (float*)d_ws;  // 1728 floats of masked packed weights

    hipMemsetAsync(out, 0, (size_t)out_size * sizeof(float), stream);  // atomic accum base
    hipLaunchKernelGGL(prep_weights, dim3(4), dim3(256), 0, stream, w1, c1, w2, c2, wb);
    hipLaunchKernelGGL(fused_block, dim3(8, 4, 64), dim3(256), 0, stream,
                       x, b1, res, wb, out);
}

// Round 8
// 147.025 us; speedup vs baseline: 1.3837x; 1.3837x over previous
//
#include <hip/hip_runtime.h>
#include <hip/hip_bf16.h>
#include <math.h>

// BasicBlockA via MFMA (bf16 in, fp32 accum), single dispatch.
// Stage 1 (all 16 latents at once): hpre[px,48] = xpatch[px,32] @ W1bt[32,48]
//   K-layout: k = ky*16 + kx*4 + ch (ky in {0,1}; kx=3 and ch=3 are zero-pad cols of B,
//   so A-frags are raw contiguous LDS reads from x stored [row][col][ch4] bf16).
// Stage 2 (mean folded into K): out[px,3] = sum over 5 live (ky,kx) of
//   hshift[px, 48] @ W2[48(->64 zero-pad), 16(3 used)]; h stored [17][18][48] bf16 so each
//   A-frag is one aligned ds_read_b128. Masked/softplus weights built in-kernel into LDS.
// Layouts per cdna_hip_programming.md S3 (m89/m91-verified): A[m=lane&15][k=quad*8+j],
// B[k=quad*8+j][n=lane&15], C col=lane&15 row=quad*4+reg.

typedef short bf16x8 __attribute__((ext_vector_type(8)));
typedef short bf16x4 __attribute__((ext_vector_type(4)));
typedef float f32x4  __attribute__((ext_vector_type(4)));

namespace {
constexpr int NC = 3, NH = 128, NW = 128;
constexpr int TS = 16;                       // output tile 16x16
constexpr int XRow = 20, XCol = 20, XCh = 4; // xs bf16 [20][20][4]
constexpr int HRow = 17, HCol = 18, HCh = 48;// hs bf16 [17][18][48] (+slack)
constexpr int W2OFF = 1536;                  // wtb: W1bt [48][32], then W2 compact [5][3][64]
constexpr int WTN = 1536 + 5 * 3 * 64;       // 2496 shorts
}

__device__ __forceinline__ float softplusf(float v) {
    return v > 20.f ? v : log1pf(expf(v));
}
__device__ __forceinline__ unsigned short f2bf(float v) {
    __hip_bfloat16 h = __float2bfloat16(v);
    return *reinterpret_cast<unsigned short*>(&h);
}

__global__ __launch_bounds__(256, 3) void fused_mfma(
    const float* __restrict__ x,  const float* __restrict__ w1,
    const float* __restrict__ c1, const float* __restrict__ bias1,
    const float* __restrict__ w2, const float* __restrict__ c2,
    const float* __restrict__ res, float* __restrict__ out)
{
    __shared__ __align__(16) unsigned short xsb[XRow * XCol * XCh];      // 1600
    __shared__ __align__(16) unsigned short hsb[HRow * HCol * HCh + 32]; // 14720
    __shared__ __align__(16) unsigned short wtb[WTN];                    // 2496

    const int tid  = threadIdx.x;
    const int b    = blockIdx.z;
    const int py0  = blockIdx.y * TS;
    const int px0  = blockIdx.x * TS;
    const int lane = tid & 63;
    const int wv   = tid >> 6;
    const int n    = lane & 15;
    const int q    = lane >> 4;

    // ---- build masked bf16 weight tables in LDS (replaces the prep dispatch) ----
    for (int e = tid; e < WTN; e += 256) {
        float v = 0.f;
        if (e < 1536) {                       // W1bt [r=l*3+i][k=ky*16+kx*4+ch]
            int r = e >> 5, k = e & 31;
            int l = r / 3, i = r - l * 3;
            int ky = k >> 4, kx = (k & 15) >> 2, j = k & 3;
            if (kx < 3 && j < 3) {
                bool live = (ky == 0) || (kx == 0) || (kx == 1 && j <= i);
                if (live) {
                    int g = ((l * 3 + i) * 3 + j) * 9 + ky * 3 + kx;
                    v = (i == j && ky == 1 && kx == 1) ? softplusf(c1[g]) : w1[g];
                }
            }
        } else {                              // W2 compact [combo][i][k=l*3+j]
            int e2 = e - 1536;
            int row = e2 >> 6, k = e2 & 63;
            int combo = row / 3, i = row - combo * 3;
            int ky = combo >= 3 ? 1 : 0, kx = combo < 3 ? combo : combo - 3;
            if (k < 48) {
                int l = k / 3, j = k - l * 3;
                bool live = (ky == 0) || (kx == 0) || (kx == 1 && j <= i);
                if (live) {
                    int g = ((l * 3 + i) * 3 + j) * 9 + ky * 3 + kx;
                    v = (i == j && ky == 1 && kx == 1) ? softplusf(c2[g]) : w2[g];
                }
            }
        }
        wtb[e] = f2bf(v);
    }

    // ---- stage x tile fp32->bf16: [20 rows][20 cols][4 ch], gy/gx = py0-2.., px0-2.. ----
    const float* xb = x + b * NC * NH * NW;
    for (int idx = tid; idx < XRow * XCol * NC; idx += 256) {
        int c  = idx % XCol;
        int r  = (idx / XCol) % XRow;
        int ch = idx / (XCol * XRow);
        int gy = py0 - 2 + r, gx = px0 - 2 + c;
        float v = 0.f;
        if ((unsigned)gy < NH && (unsigned)gx < NW) v = xb[ch * NH * NW + gy * NW + gx];
        xsb[(r * XCol + c) * XCh + ch] = f2bf(v);
    }
    for (int idx = tid; idx < XRow * XCol; idx += 256) xsb[idx * XCh + 3] = 0; // ch pad
    for (int idx = tid; idx < 32; idx += 256) hsb[HRow * HCol * HCh + idx] = 0; // slack

    float rg; { float rv = res[0]; rg = rv > 0.f ? rv : 0.f; }
    float bf0 = bias1[n], bf1 = bias1[16 + n], bf2 = bias1[32 + n];

    __syncthreads();  // xsb + wtb ready

    // ---- stage-1 B-frags from LDS table ----
    bf16x8 b1f0 = *(const bf16x8*)(wtb + (0 * 16 + n) * 32 + q * 8);
    bf16x8 b1f1 = *(const bf16x8*)(wtb + (1 * 16 + n) * 32 + q * 8);
    bf16x8 b1f2 = *(const bf16x8*)(wtb + (2 * 16 + n) * 32 + q * 8);

    // ---- stage 1: 34 M-tiles (17 h-rows x col-bases {-1,1}), waves round-robin ----
    for (int t = wv; t < 34; t += 4) {
        int py = (t >> 1) - 1;              // h row -1..15
        int cb = (t & 1) ? 1 : -1;          // h col base
        int rowxs = py + 1 + (q >> 1);      // ky = q>>1
        int colxs = cb + n + 1 + ((q & 1) << 1);
        const unsigned short* ap = xsb + (rowxs * XCol + colxs) * XCh;
        bf16x4 lo = *(const bf16x4*)ap;
        bf16x4 hi = *(const bf16x4*)(ap + 4);
        bf16x8 af;
        af[0] = lo[0]; af[1] = lo[1]; af[2] = lo[2]; af[3] = lo[3];
        af[4] = hi[0]; af[5] = hi[1]; af[6] = hi[2]; af[7] = hi[3];
        f32x4 z = {0.f, 0.f, 0.f, 0.f};
        f32x4 c0 = __builtin_amdgcn_mfma_f32_16x16x32_bf16(af, b1f0, z, 0, 0, 0);
        f32x4 c1 = __builtin_amdgcn_mfma_f32_16x16x32_bf16(af, b1f1, z, 0, 0, 0);
        f32x4 c2 = __builtin_amdgcn_mfma_f32_16x16x32_bf16(af, b1f2, z, 0, 0, 0);
        int gy = py0 + py;
        float rmk = ((unsigned)gy < NH) ? 1.f : 0.f;
        unsigned short* hrow = hsb + (py + 1) * HCol * HCh;
        #pragma unroll
        for (int r = 0; r < 4; ++r) {
            int pxl = cb + q * 4 + r;       // h col -1..16 (C row m = q*4+r)
            int gx  = px0 + pxl;
            float mk = rmk * (((unsigned)gx < NW) ? 1.f : 0.f);
            float v0 = c0[r] + bf0; v0 = (v0 > 0.f ? v0 : __expf(v0) - 1.f) * mk;
            float v1 = c1[r] + bf1; v1 = (v1 > 0.f ? v1 : __expf(v1) - 1.f) * mk;
            float v2 = c2[r] + bf2; v2 = (v2 > 0.f ? v2 : __expf(v2) - 1.f) * mk;
            unsigned short* hp = hrow + (pxl + 1) * HCh + n;
            hp[0]  = f2bf(v0);
            hp[16] = f2bf(v1);
            hp[32] = f2bf(v2);
        }
    }

    // ---- stage-2 B-frags (lanes n>=3 are zero columns) ----
    bf16x8 b2f[5][2];
    #pragma unroll
    for (int c = 0; c < 5; ++c) {
        if (n < 3) {
            b2f[c][0] = *(const bf16x8*)(wtb + W2OFF + (c * 3 + n) * 64 + q * 8);
            b2f[c][1] = *(const bf16x8*)(wtb + W2OFF + (c * 3 + n) * 64 + 32 + q * 8);
        } else {
            #pragma unroll
            for (int j = 0; j < 8; ++j) { b2f[c][0][j] = 0; b2f[c][1][j] = 0; }
        }
    }

    __syncthreads();  // hsb ready

    // ---- stage 2: per out row, 5 live (ky,kx) x (K=48 in 2 MFMA) ----
    const int kyv[5] = {0, 0, 0, 1, 1};
    const int kxv[5] = {0, 1, 2, 0, 1};
    float* ob = out + b * NC * NH * NW;
    #pragma unroll 1
    for (int s = 0; s < 4; ++s) {
        int py = wv + s * 4;                // out row 0..15
        f32x4 accA = {0.f, 0.f, 0.f, 0.f};
        f32x4 accB = {0.f, 0.f, 0.f, 0.f};
        #pragma unroll
        for (int c = 0; c < 5; ++c) {
            const unsigned short* hp =
                hsb + ((py + kyv[c]) * HCol + n + kxv[c]) * HCh + q * 8;
            bf16x8 a0 = *(const bf16x8*)hp;
            bf16x8 a1 = *(const bf16x8*)(hp + 32);
            if (c & 1) {
                accB = __builtin_amdgcn_mfma_f32_16x16x32_bf16(a0, b2f[c][0], accB, 0, 0, 0);
                accB = __builtin_amdgcn_mfma_f32_16x16x32_bf16(a1, b2f[c][1], accB, 0, 0, 0);
            } else {
                accA = __builtin_amdgcn_mfma_f32_16x16x32_bf16(a0, b2f[c][0], accA, 0, 0, 0);
                accA = __builtin_amdgcn_mfma_f32_16x16x32_bf16(a1, b2f[c][1], accA, 0, 0, 0);
            }
        }
        if (n < 3) {                         // lanes with a real out channel
            int gy = py0 + py;
            const float* xp = xb + n * NH * NW + gy * NW + px0;
            float*       op = ob + n * NH * NW + gy * NW + px0;
            float4 xv = *(const float4*)(xp + q * 4);
            float4 o;
            o.x = (accA[0] + accB[0]) * (1.f / 16.f) + rg * xv.x;
            o.y = (accA[1] + accB[1]) * (1.f / 16.f) + rg * xv.y;
            o.z = (accA[2] + accB[2]) * (1.f / 16.f) + rg * xv.z;
            o.w = (accA[3] + accB[3]) * (1.f / 16.f) + rg * xv.w;
            *(float4*)(op + q * 4) = o;
        }
    }
}

extern "C" void kernel_launch(void* const* d_in, const int* in_sizes, int n_in,
                              void* d_out, int out_size, void* d_ws, size_t ws_size,
                              hipStream_t stream) {
    (void)in_sizes; (void)n_in; (void)out_size; (void)d_ws; (void)ws_size;
    const float* x   = (const float*)d_in[0];
    const float* w1  = (const float*)d_in[1];
    const float* c1  = (const float*)d_in[2];
    const float* b1  = (const float*)d_in[3];
    const float* w2  = (const float*)d_in[4];
    const float* c2  = (const float*)d_in[5];
    const float* res = (const float*)d_in[6];
    float* out = (float*)d_out;

    hipLaunchKernelGGL(fused_mfma, dim3(NW / TS, NH / TS, 64), dim3(256), 0, stream,
                       x, w1, c1, b1, w2, c2, res, out);
}

// Round 10
// 128.689 us; speedup vs baseline: 1.5808x; 1.1425x over previous
//
#include <hip/hip_runtime.h>
#include <hip/hip_bf16.h>
#include <math.h>

// BasicBlockA via MFMA (bf16 in, fp32 accum). R10 = R9 + fix: boundary-mask LDS fill
// covered only 256 of 320 slots (tiles t>=16 read uninit LDS -> inf). Now strided loop.
//  (1) stage-1 flat-pixel M-tiling: 306 h-px as 20 M-tiles (was 34 w/ 56% slot util)
//  (2) weight tables pre-swizzled into d_ws by a prep kernel; B-frags loaded as
//      coalesced 16B global reads (removes per-block softplus/divmod table build)
//  (3) boundary masks precomputed in LDS; one ds_read_b128 per stage-1 tile
//  (4) W1 channel permutation (lane n -> channels 3n..3n+2) so h-writes are contiguous
// Layouts (m89/m91-verified): A[m=lane&15][k=q*8+j], B[k=q*8+j][n=lane&15],
// C col=lane&15, row=q*4+reg.

typedef short bf16x8 __attribute__((ext_vector_type(8)));
typedef short bf16x4 __attribute__((ext_vector_type(4)));
typedef float f32x4  __attribute__((ext_vector_type(4)));

namespace {
constexpr int NC = 3, NH = 128, NW = 128;
constexpr int TS = 16;                        // output tile 16x16
constexpr int XRow = 20, XCol = 20, XCh = 4;  // xs bf16 [20][20][4]
constexpr int NT  = 20;                       // stage-1 M-tiles (20*16 = 320 slots)
constexpr int W2OFF = 1536;                   // shorts: w1tab 3*64*8, w2tab 5*2*64*8
constexpr int WTN   = 1536 + 5120;            // 6656 shorts = 13312 B in d_ws
}

__device__ __forceinline__ float softplusf(float v) {
    return v > 20.f ? v : log1pf(expf(v));
}
__device__ __forceinline__ unsigned short f2bf(float v) {   // RNE (prep only)
    __hip_bfloat16 h = __float2bfloat16(v);
    return *reinterpret_cast<unsigned short*>(&h);
}
__device__ __forceinline__ unsigned short rne(float v) {    // manual RNE, cheap
    unsigned u = __float_as_uint(v);
    u += 0x7FFF + ((u >> 16) & 1);
    return (unsigned short)(u >> 16);
}

// Build swizzled bf16 weight fragments in d_ws.
// w1tab [f(3)][lane(64)][8]: B-frag for stage-1 frag f; column n -> (l=n, i=f);
//   k=q*8+j -> ky=k>>4, kx=(k>>2)&3, ch=k&3 (kx==3 / ch==3 zero-pad).
// w2tab [c(5)][m(2)][lane(64)][8]: combo c=(ky,kx), K=m*32+q*8+j = l*3+jj (<48),
//   column n = out channel (n>=3 zero).
__global__ void prep_weights(const float* __restrict__ w1, const float* __restrict__ c1,
                             const float* __restrict__ w2, const float* __restrict__ c2,
                             unsigned short* __restrict__ tab) {
    int e = blockIdx.x * 256 + threadIdx.x;
    if (e >= WTN) return;
    float v = 0.f;
    if (e < W2OFF) {
        int f = e >> 9, lane = (e >> 3) & 63, j = e & 7;
        int n = lane & 15, q = lane >> 4;
        int k = q * 8 + j;
        int ky = k >> 4, kx = (k >> 2) & 3, ch = k & 3;
        if (kx < 3 && ch < 3) {
            bool live = (ky == 0) || (kx == 0) || (kx == 1 && ch <= f);
            if (live) {
                int g = ((n * 3 + f) * 3 + ch) * 9 + ky * 3 + kx;
                v = (f == ch && ky == 1 && kx == 1) ? softplusf(c1[g]) : w1[g];
            }
        }
    } else {
        int e2 = e - W2OFF;
        int c = e2 >> 10, m = (e2 >> 9) & 1, lane = (e2 >> 3) & 63, j = e2 & 7;
        int n = lane & 15, q = lane >> 4;
        const int kyv[5] = {0, 0, 0, 1, 1};
        const int kxv[5] = {0, 1, 2, 0, 1};
        int ky = kyv[c], kx = kxv[c];
        int K = m * 32 + q * 8 + j;
        if (n < 3 && K < 48) {
            int l = K / 3, jj = K - l * 3;
            bool live = (ky == 0) || (kx == 0) || (kx == 1 && jj <= n);
            if (live) {
                int g = ((l * 3 + n) * 3 + jj) * 9 + ky * 3 + kx;
                v = (n == jj && ky == 1 && kx == 1) ? softplusf(c2[g]) : w2[g];
            }
        }
    }
    tab[e] = f2bf(v);
}

__global__ __launch_bounds__(256, 4) void fused_mfma(
    const float* __restrict__ x, const float* __restrict__ bias1,
    const float* __restrict__ res, const unsigned short* __restrict__ tab,
    float* __restrict__ out)
{
    __shared__ __align__(16) unsigned short xsb[XRow * XCol * XCh];  // 3200 B
    __shared__ __align__(16) unsigned short hsb[NT * 16 * 48];       // 30720 B
    __shared__ __align__(16) float          mskf[NT * 16];           // 1280 B

    const int tid  = threadIdx.x;
    const int b    = blockIdx.z;
    const int py0  = blockIdx.y * TS;
    const int px0  = blockIdx.x * TS;
    const int lane = tid & 63;
    const int wv   = tid >> 6;
    const int n    = lane & 15;
    const int q    = lane >> 4;

    // ---- stage x tile fp32->bf16 packed [r][c][4]: one px (3 loads + b64 write) / iter ----
    const float* xb = x + b * NC * NH * NW;
    #pragma unroll
    for (int it = 0; it < 2; ++it) {
        unsigned p = tid + it * 256;
        if (p < XRow * XCol) {
            unsigned r = p / XCol, c = p - r * XCol;
            int gy = (int)(py0 - 2 + r), gx = (int)(px0 - 2 + c);
            bool ok = ((unsigned)gy < NH) && ((unsigned)gx < NW);
            const float* sp = xb + gy * NW + gx;
            float v0 = ok ? sp[0]           : 0.f;
            float v1 = ok ? sp[NH * NW]     : 0.f;
            float v2 = ok ? sp[2 * NH * NW] : 0.f;
            unsigned short s[4] = {rne(v0), rne(v1), rne(v2), 0};
            *(bf16x4*)(xsb + p * 4) = *(const bf16x4*)s;
        }
    }
    // ---- boundary masks for ALL 320 M-slots (fix: was tid<320 with 256 threads) ----
    for (unsigned p = tid; p < NT * 16; p += 256) {
        unsigned pr = p / 18, pc = p - pr * 18;
        int gy = (int)(py0 + pr) - 1, gx = (int)(px0 + pc) - 1;
        mskf[p] = (((unsigned)gy < NH) && ((unsigned)gx < NW)) ? 1.f : 0.f;
    }

    float rg; { float rv = res[0]; rg = rv > 0.f ? rv : 0.f; }
    // bias for permuted channels: lane n, frag f -> channel 3n+f
    float bf0 = bias1[3 * n], bf1 = bias1[3 * n + 1], bf2 = bias1[3 * n + 2];

    // stage-1 B-frags: coalesced 16B global loads (L2-hot table)
    bf16x8 b1f0 = *(const bf16x8*)(tab + (0 * 64 + lane) * 8);
    bf16x8 b1f1 = *(const bf16x8*)(tab + (1 * 64 + lane) * 8);
    bf16x8 b1f2 = *(const bf16x8*)(tab + (2 * 64 + lane) * 8);

    __syncthreads();  // xsb + mskf ready

    // ---- stage 1: 20 flat-px M-tiles, waves round-robin (5 each) ----
    #pragma unroll 1
    for (int t = wv; t < NT; t += 4) {
        unsigned p  = t * 16 + n;                 // A-row pixel
        unsigned pr = p / 18, pc = p - pr * 18;
        const unsigned short* ap =
            xsb + ((pr + (q >> 1)) * XCol + pc + ((q & 1) << 1)) * 4;
        bf16x4 lo = *(const bf16x4*)ap;
        bf16x4 hi = *(const bf16x4*)(ap + 4);
        bf16x8 af;
        #pragma unroll
        for (int j = 0; j < 4; ++j) { af[j] = lo[j]; af[4 + j] = hi[j]; }
        f32x4 z = {0.f, 0.f, 0.f, 0.f};
        f32x4 c0 = __builtin_amdgcn_mfma_f32_16x16x32_bf16(af, b1f0, z, 0, 0, 0);
        f32x4 c1 = __builtin_amdgcn_mfma_f32_16x16x32_bf16(af, b1f1, z, 0, 0, 0);
        f32x4 c2 = __builtin_amdgcn_mfma_f32_16x16x32_bf16(af, b1f2, z, 0, 0, 0);
        float4 mk4 = *(const float4*)(mskf + t * 16 + q * 4);
        float mk[4] = {mk4.x, mk4.y, mk4.z, mk4.w};
        unsigned short* hp = hsb + (t * 16 + q * 4) * 48 + 3 * n;
        #pragma unroll
        for (int r = 0; r < 4; ++r) {
            float v0 = c0[r] + bf0; v0 = (v0 > 0.f ? v0 : __expf(v0) - 1.f) * mk[r];
            float v1 = c1[r] + bf1; v1 = (v1 > 0.f ? v1 : __expf(v1) - 1.f) * mk[r];
            float v2 = c2[r] + bf2; v2 = (v2 > 0.f ? v2 : __expf(v2) - 1.f) * mk[r];
            hp[r * 48 + 0] = rne(v0);
            hp[r * 48 + 1] = rne(v1);
            hp[r * 48 + 2] = rne(v2);
        }
    }

    // stage-2 B-frags: 10 coalesced 16B loads, issued before the barrier
    bf16x8 b2f[5][2];
    #pragma unroll
    for (int c = 0; c < 5; ++c) {
        b2f[c][0] = *(const bf16x8*)(tab + W2OFF + ((c * 2 + 0) * 64 + lane) * 8);
        b2f[c][1] = *(const bf16x8*)(tab + W2OFF + ((c * 2 + 1) * 64 + lane) * 8);
    }

    __syncthreads();  // hsb ready

    // ---- stage 2: out[px,3] = sum over 5 live (ky,kx), K=48(->64) in 2 MFMA ----
    const int kyv[5] = {0, 0, 0, 1, 1};
    const int kxv[5] = {0, 1, 2, 0, 1};
    float* ob = out + b * NC * NH * NW;
    #pragma unroll 1
    for (int s = 0; s < 4; ++s) {
        int py = wv + s * 4;                 // out row 0..15
        f32x4 accA = {0.f, 0.f, 0.f, 0.f};
        f32x4 accB = {0.f, 0.f, 0.f, 0.f};
        #pragma unroll
        for (int c = 0; c < 5; ++c) {
            const unsigned short* hp =
                hsb + ((py + kyv[c]) * 18 + n + kxv[c]) * 48 + q * 8;
            bf16x8 a0 = *(const bf16x8*)hp;
            bf16x8 a1 = *(const bf16x8*)(hp + 32);
            if (c & 1) {
                accB = __builtin_amdgcn_mfma_f32_16x16x32_bf16(a0, b2f[c][0], accB, 0, 0, 0);
                accB = __builtin_amdgcn_mfma_f32_16x16x32_bf16(a1, b2f[c][1], accB, 0, 0, 0);
            } else {
                accA = __builtin_amdgcn_mfma_f32_16x16x32_bf16(a0, b2f[c][0], accA, 0, 0, 0);
                accA = __builtin_amdgcn_mfma_f32_16x16x32_bf16(a1, b2f[c][1], accA, 0, 0, 0);
            }
        }
        if (n < 3) {                          // lanes with a real out channel
            int gy = py0 + py;
            const float* xp = xb + n * NH * NW + gy * NW + px0;
            float*       op = ob + n * NH * NW + gy * NW + px0;
            float4 xv = *(const float4*)(xp + q * 4);
            float4 o;
            o.x = (accA[0] + accB[0]) * (1.f / 16.f) + rg * xv.x;
            o.y = (accA[1] + accB[1]) * (1.f / 16.f) + rg * xv.y;
            o.z = (accA[2] + accB[2]) * (1.f / 16.f) + rg * xv.z;
            o.w = (accA[3] + accB[3]) * (1.f / 16.f) + rg * xv.w;
            *(float4*)(op + q * 4) = o;
        }
    }
}

extern "C" void kernel_launch(void* const* d_in, const int* in_sizes, int n_in,
                              void* d_out, int out_size, void* d_ws, size_t ws_size,
                              hipStream_t stream) {
    (void)in_sizes; (void)n_in; (void)out_size; (void)ws_size;
    const float* x   = (const float*)d_in[0];
    const float* w1  = (const float*)d_in[1];
    const float* c1  = (const float*)d_in[2];
    const float* b1  = (const float*)d_in[3];
    const float* w2  = (const float*)d_in[4];
    const float* c2  = (const float*)d_in[5];
    const float* res = (const float*)d_in[6];
    float* out = (float*)d_out;
    unsigned short* tab = (unsigned short*)d_ws;   // 13312 B of swizzled bf16 weights

    hipLaunchKernelGGL(prep_weights, dim3((WTN + 255) / 256), dim3(256), 0, stream,
                       w1, c1, w2, c2, tab);
    hipLaunchKernelGGL(fused_mfma, dim3(NW / TS, NH / TS, 64), dim3(256), 0, stream,
                       x, b1, res, tab, out);
}

// Round 11
// 105.098 us; speedup vs baseline: 1.9357x; 1.2245x over previous
//
#include <hip/hip_runtime.h>
#include <hip/hip_bf16.h>
#include <math.h>

// BasicBlockA via MFMA (bf16 in, fp32 accum). R11 = R10 with stage-1 TRANSPOSED:
//   C[m=channel][n=pixel] (A=weights, B=x-patch). Benefits:
//   - lane holds 4 consecutive channels -> h-write is 3 aligned ds_write_b64 (was 12 b16)
//   - boundary mask = function of lane's own pixel (same divmod as B-frag) -> mask table gone
//   - LDS 32.6KB -> 5 blocks/CU (was 4 at 35.3KB); __launch_bounds__(256,5)
// Stage 2 unchanged from R10. Layouts (m89/m91): A[m=lane&15][k=q*8+j],
// B[k=q*8+j][n=lane&15], C col=lane&15 row=q*4+reg.

typedef short bf16x8 __attribute__((ext_vector_type(8)));
typedef short bf16x4 __attribute__((ext_vector_type(4)));
typedef float f32x4  __attribute__((ext_vector_type(4)));

namespace {
constexpr int NC = 3, NH = 128, NW = 128;
constexpr int TS = 16;                        // output tile 16x16
constexpr int XRow = 20, XCol = 20;           // xs bf16 [20][20][4]
constexpr int NPX = 306;                      // h pixels: 17 rows x 18 cols (flat)
constexpr int NT  = 20;                       // stage-1 M-tiles (20*16 = 320 slots)
constexpr int W2OFF = 1536;                   // shorts: w1tab 3*64*8, w2tab 5*2*64*8
constexpr int WTN   = 1536 + 5120;            // 6656 shorts = 13312 B in d_ws
}

__device__ __forceinline__ float softplusf(float v) {
    return v > 20.f ? v : log1pf(expf(v));
}
__device__ __forceinline__ unsigned short f2bf(float v) {   // RNE (prep only)
    __hip_bfloat16 h = __float2bfloat16(v);
    return *reinterpret_cast<unsigned short*>(&h);
}
__device__ __forceinline__ unsigned short rne(float v) {    // manual RNE, cheap
    unsigned u = __float_as_uint(v);
    u += 0x7FFF + ((u >> 16) & 1);
    return (unsigned short)(u >> 16);
}

// w1tab [f(3)][lane(64)][8]: stage-1 A-frag; m=lane&15 -> channel ch=f*16+m (=l*3+i),
//   k=q*8+j -> ky=k>>4, kx=(k>>2)&3, chin=k&3 (kx==3 / chin==3 zero-pad).
// w2tab [c(5)][m(2)][lane(64)][8]: stage-2 B-frag; combo c=(ky,kx), K=m*32+q*8+j=l*3+jj,
//   column n = out channel (n>=3 zero).
__global__ void prep_weights(const float* __restrict__ w1, const float* __restrict__ c1,
                             const float* __restrict__ w2, const float* __restrict__ c2,
                             unsigned short* __restrict__ tab) {
    int e = blockIdx.x * 256 + threadIdx.x;
    if (e >= WTN) return;
    float v = 0.f;
    if (e < W2OFF) {
        int f = e >> 9, lane = (e >> 3) & 63, j = e & 7;
        int m = lane & 15, q = lane >> 4;
        int k = q * 8 + j;
        int ky = k >> 4, kx = (k >> 2) & 3, chin = k & 3;
        int ch = f * 16 + m;                 // output channel of stage 1 (= l*3+i)
        if (kx < 3 && chin < 3 && ch < 48) {
            int l = ch / 3, i = ch - l * 3;
            bool live = (ky == 0) || (kx == 0) || (kx == 1 && chin <= i);
            if (live) {
                int g = ((l * 3 + i) * 3 + chin) * 9 + ky * 3 + kx;
                v = (i == chin && ky == 1 && kx == 1) ? softplusf(c1[g]) : w1[g];
            }
        }
    } else {
        int e2 = e - W2OFF;
        int c = e2 >> 10, m = (e2 >> 9) & 1, lane = (e2 >> 3) & 63, j = e2 & 7;
        int n = lane & 15, q = lane >> 4;
        const int kyv[5] = {0, 0, 0, 1, 1};
        const int kxv[5] = {0, 1, 2, 0, 1};
        int ky = kyv[c], kx = kxv[c];
        int K = m * 32 + q * 8 + j;
        if (n < 3 && K < 48) {
            int l = K / 3, jj = K - l * 3;
            bool live = (ky == 0) || (kx == 0) || (kx == 1 && jj <= n);
            if (live) {
                int g = ((l * 3 + n) * 3 + jj) * 9 + ky * 3 + kx;
                v = (n == jj && ky == 1 && kx == 1) ? softplusf(c2[g]) : w2[g];
            }
        }
    }
    tab[e] = f2bf(v);
}

__global__ __launch_bounds__(256, 5) void fused_mfma(
    const float* __restrict__ x, const float* __restrict__ bias1,
    const float* __restrict__ res, const unsigned short* __restrict__ tab,
    float* __restrict__ out)
{
    __shared__ __align__(16) unsigned short xsb[XRow * XCol * 4];  // 3200 B
    __shared__ __align__(16) unsigned short hsb[NPX * 48];         // 29376 B

    const int tid  = threadIdx.x;
    const int b    = blockIdx.z;
    const int py0  = blockIdx.y * TS;
    const int px0  = blockIdx.x * TS;
    const int lane = tid & 63;
    const int wv   = tid >> 6;
    const int n    = lane & 15;
    const int q    = lane >> 4;

    // ---- stage x tile fp32->bf16 packed [r][c][4] ----
    const float* xb = x + b * NC * NH * NW;
    #pragma unroll
    for (int it = 0; it < 2; ++it) {
        unsigned p = tid + it * 256;
        if (p < XRow * XCol) {
            unsigned r = p / XCol, c = p - r * XCol;
            int gy = (int)(py0 - 2 + r), gx = (int)(px0 - 2 + c);
            bool ok = ((unsigned)gy < NH) && ((unsigned)gx < NW);
            const float* sp = xb + gy * NW + gx;
            float v0 = ok ? sp[0]           : 0.f;
            float v1 = ok ? sp[NH * NW]     : 0.f;
            float v2 = ok ? sp[2 * NH * NW] : 0.f;
            unsigned short s[4] = {rne(v0), rne(v1), rne(v2), 0};
            *(bf16x4*)(xsb + p * 4) = *(const bf16x4*)s;
        }
    }

    float rg; { float rv = res[0]; rg = rv > 0.f ? rv : 0.f; }
    // bias for channels f*16 + q*4 + r (r=0..3), f=0..2 -- 16B-aligned float4 loads
    float4 b4[3];
    #pragma unroll
    for (int f = 0; f < 3; ++f) b4[f] = *(const float4*)(bias1 + f * 16 + q * 4);

    // stage-1 A-frags (weights): coalesced 16B global loads (L2-hot table)
    bf16x8 a1f0 = *(const bf16x8*)(tab + (0 * 64 + lane) * 8);
    bf16x8 a1f1 = *(const bf16x8*)(tab + (1 * 64 + lane) * 8);
    bf16x8 a1f2 = *(const bf16x8*)(tab + (2 * 64 + lane) * 8);

    __syncthreads();  // xsb ready

    // ---- stage 1: 20 flat-px M-tiles, waves round-robin (5 each) ----
    #pragma unroll 1
    for (int t = wv; t < NT; t += 4) {
        unsigned p  = t * 16 + n;                 // this lane's pixel (B column)
        unsigned pr = p / 18, pc = p - pr * 18;
        const unsigned short* bp =
            xsb + ((pr + (q >> 1)) * XCol + pc + ((q & 1) << 1)) * 4;
        bf16x4 lo = *(const bf16x4*)bp;
        bf16x4 hi = *(const bf16x4*)(bp + 4);
        bf16x8 bf;
        #pragma unroll
        for (int j = 0; j < 4; ++j) { bf[j] = lo[j]; bf[4 + j] = hi[j]; }
        f32x4 z = {0.f, 0.f, 0.f, 0.f};
        f32x4 c0 = __builtin_amdgcn_mfma_f32_16x16x32_bf16(a1f0, bf, z, 0, 0, 0);
        f32x4 c1 = __builtin_amdgcn_mfma_f32_16x16x32_bf16(a1f1, bf, z, 0, 0, 0);
        f32x4 c2 = __builtin_amdgcn_mfma_f32_16x16x32_bf16(a1f2, bf, z, 0, 0, 0);
        // mask for this pixel (h row pr-1, col pc-1 in image coords)
        float mk = (((unsigned)(py0 + (int)pr - 1) < NH) &&
                    ((unsigned)(px0 + (int)pc - 1) < NW)) ? 1.f : 0.f;
        if (p < NPX) {
            unsigned short s0[4], s1[4], s2[4];
            #pragma unroll
            for (int r = 0; r < 4; ++r) {
                float v0 = c0[r] + ((const float*)&b4[0])[r];
                float v1 = c1[r] + ((const float*)&b4[1])[r];
                float v2 = c2[r] + ((const float*)&b4[2])[r];
                v0 = (v0 > 0.f ? v0 : __expf(v0) - 1.f) * mk;
                v1 = (v1 > 0.f ? v1 : __expf(v1) - 1.f) * mk;
                v2 = (v2 > 0.f ? v2 : __expf(v2) - 1.f) * mk;
                s0[r] = rne(v0); s1[r] = rne(v1); s2[r] = rne(v2);
            }
            unsigned short* hp = hsb + p * 48 + q * 4;
            *(bf16x4*)(hp +  0) = *(const bf16x4*)s0;   // ch  q*4..q*4+3
            *(bf16x4*)(hp + 16) = *(const bf16x4*)s1;   // ch 16+q*4..
            *(bf16x4*)(hp + 32) = *(const bf16x4*)s2;   // ch 32+q*4..
        }
    }

    // stage-2 B-frags: 10 coalesced 16B loads, issued before the barrier
    bf16x8 b2f[5][2];
    #pragma unroll
    for (int c = 0; c < 5; ++c) {
        b2f[c][0] = *(const bf16x8*)(tab + W2OFF + ((c * 2 + 0) * 64 + lane) * 8);
        b2f[c][1] = *(const bf16x8*)(tab + W2OFF + ((c * 2 + 1) * 64 + lane) * 8);
    }

    __syncthreads();  // hsb ready

    // ---- stage 2: out[px,3] = sum over 5 live (ky,kx), K=48(->64) in 2 MFMA ----
    const int kyv[5] = {0, 0, 0, 1, 1};
    const int kxv[5] = {0, 1, 2, 0, 1};
    float* ob = out + b * NC * NH * NW;
    #pragma unroll 1
    for (int s = 0; s < 4; ++s) {
        int py = wv + s * 4;                 // out row 0..15
        f32x4 accA = {0.f, 0.f, 0.f, 0.f};
        f32x4 accB = {0.f, 0.f, 0.f, 0.f};
        #pragma unroll
        for (int c = 0; c < 5; ++c) {
            const unsigned short* hp =
                hsb + ((py + kyv[c]) * 18 + n + kxv[c]) * 48 + q * 8;
            bf16x8 a0 = *(const bf16x8*)hp;
            bf16x8 a1 = *(const bf16x8*)(hp + 32);
            if (c & 1) {
                accB = __builtin_amdgcn_mfma_f32_16x16x32_bf16(a0, b2f[c][0], accB, 0, 0, 0);
                accB = __builtin_amdgcn_mfma_f32_16x16x32_bf16(a1, b2f[c][1], accB, 0, 0, 0);
            } else {
                accA = __builtin_amdgcn_mfma_f32_16x16x32_bf16(a0, b2f[c][0], accA, 0, 0, 0);
                accA = __builtin_amdgcn_mfma_f32_16x16x32_bf16(a1, b2f[c][1], accA, 0, 0, 0);
            }
        }
        if (n < 3) {                          // lanes with a real out channel
            int gy = py0 + py;
            const float* xp = xb + n * NH * NW + gy * NW + px0;
            float*       op = ob + n * NH * NW + gy * NW + px0;
            float4 xv = *(const float4*)(xp + q * 4);
            float4 o;
            o.x = (accA[0] + accB[0]) * (1.f / 16.f) + rg * xv.x;
            o.y = (accA[1] + accB[1]) * (1.f / 16.f) + rg * xv.y;
            o.z = (accA[2] + accB[2]) * (1.f / 16.f) + rg * xv.z;
            o.w = (accA[3] + accB[3]) * (1.f / 16.f) + rg * xv.w;
            *(float4*)(op + q * 4) = o;
        }
    }
}

extern "C" void kernel_launch(void* const* d_in, const int* in_sizes, int n_in,
                              void* d_out, int out_size, void* d_ws, size_t ws_size,
                              hipStream_t stream) {
    (void)in_sizes; (void)n_in; (void)out_size; (void)ws_size;
    const float* x   = (const float*)d_in[0];
    const float* w1  = (const float*)d_in[1];
    const float* c1  = (const float*)d_in[2];
    const float* b1  = (const float*)d_in[3];
    const float* w2  = (const float*)d_in[4];
    const float* c2  = (const float*)d_in[5];
    const float* res = (const float*)d_in[6];
    float* out = (float*)d_out;
    unsigned short* tab = (unsigned short*)d_ws;   // 13312 B of swizzled bf16 weights

    hipLaunchKernelGGL(prep_weights, dim3((WTN + 255) / 256), dim3(256), 0, stream,
                       w1, c1, w2, c2, tab);
    hipLaunchKernelGGL(fused_mfma, dim3(NW / TS, NH / TS, 64), dim3(256), 0, stream,
                       x, b1, res, tab, out);
}

// Round 12
// 103.747 us; speedup vs baseline: 1.9609x; 1.0130x over previous
//
#include <hip/hip_runtime.h>
#include <hip/hip_bf16.h>
#include <math.h>

// BasicBlockA via MFMA (bf16 in, fp32 accum). R12 = R11 + stage-2 K-folding:
//   out[px,ch] = sum over K=240 (5 shift-combos x 48 h-channels, pad->256) in 8 MFMAs
//   per out row (was 5 combos x 2 MFMAs = 10, each K=64 w/ 16 pad). A-frag for MFMA m is
//   one b128 at base(py,n) + delta_m, delta_m lane-constant across rows (k>=240 -> delta 0,
//   B columns zero). 4 accumulators (m&3) cut dependent-MFMA chains 6 -> 2.
// Stage 1 unchanged from R11 (transposed C[m=ch][n=px], mask from lane's own pixel).
// Layouts (m89/m91): A[m=lane&15][k=q*8+j], B[k=q*8+j][n=lane&15], C col=lane&15 row=q*4+reg.

typedef short bf16x8 __attribute__((ext_vector_type(8)));
typedef short bf16x4 __attribute__((ext_vector_type(4)));
typedef float f32x4  __attribute__((ext_vector_type(4)));

namespace {
constexpr int NC = 3, NH = 128, NW = 128;
constexpr int TS = 16;                        // output tile 16x16
constexpr int XRow = 20, XCol = 20;           // xs bf16 [20][20][4]
constexpr int NPX = 306;                      // h pixels: 17 rows x 18 cols (flat)
constexpr int NT  = 20;                       // stage-1 M-tiles (20*16 = 320 slots)
constexpr int W2OFF = 1536;                   // shorts: w1tab 3*64*8, w2tab 8*64*8
constexpr int WTN   = 1536 + 4096;            // 5632 shorts = 11264 B in d_ws
}

__device__ __forceinline__ float softplusf(float v) {
    return v > 20.f ? v : log1pf(expf(v));
}
__device__ __forceinline__ unsigned short f2bf(float v) {   // RNE (prep only)
    __hip_bfloat16 h = __float2bfloat16(v);
    return *reinterpret_cast<unsigned short*>(&h);
}
__device__ __forceinline__ unsigned short rne(float v) {    // manual RNE, cheap
    unsigned u = __float_as_uint(v);
    u += 0x7FFF + ((u >> 16) & 1);
    return (unsigned short)(u >> 16);
}

// w1tab [f(3)][lane(64)][8]: stage-1 A-frag; m=lane&15 -> channel ch=f*16+m (=l*3+i),
//   k=q*8+j -> ky=k>>4, kx=(k>>2)&3, chin=k&3 (kx==3 / chin==3 zero-pad).
// w2tab [mfma m(8)][lane(64)][8]: stage-2 B-frag, K-folded: k=m*32+q*8+j;
//   k<240: combo c=k/48 (ky=c>=3, kx=c-3*ky), ch=k%48 (l=ch/3, jj=ch%3);
//   column n = out channel (n>=3 or k>=240 -> zero).
__global__ void prep_weights(const float* __restrict__ w1, const float* __restrict__ c1,
                             const float* __restrict__ w2, const float* __restrict__ c2,
                             unsigned short* __restrict__ tab) {
    int e = blockIdx.x * 256 + threadIdx.x;
    if (e >= WTN) return;
    float v = 0.f;
    if (e < W2OFF) {
        int f = e >> 9, lane = (e >> 3) & 63, j = e & 7;
        int m = lane & 15, q = lane >> 4;
        int k = q * 8 + j;
        int ky = k >> 4, kx = (k >> 2) & 3, chin = k & 3;
        int ch = f * 16 + m;                 // output channel of stage 1 (= l*3+i)
        if (kx < 3 && chin < 3 && ch < 48) {
            int l = ch / 3, i = ch - l * 3;
            bool live = (ky == 0) || (kx == 0) || (kx == 1 && chin <= i);
            if (live) {
                int g = ((l * 3 + i) * 3 + chin) * 9 + ky * 3 + kx;
                v = (i == chin && ky == 1 && kx == 1) ? softplusf(c1[g]) : w1[g];
            }
        }
    } else {
        int e2 = e - W2OFF;
        int mf = e2 >> 9, lane = (e2 >> 3) & 63, j = e2 & 7;
        int n = lane & 15, q = lane >> 4;
        int k = mf * 32 + q * 8 + j;
        if (n < 3 && k < 240) {
            int c  = k / 48, ch = k - c * 48;
            int ky = (c >= 3) ? 1 : 0, kx = c - 3 * ky;
            int l = ch / 3, jj = ch - l * 3;
            bool live = (ky == 0) || (kx == 0) || (kx == 1 && jj <= n);
            if (live) {
                int g = ((l * 3 + n) * 3 + jj) * 9 + ky * 3 + kx;
                v = (n == jj && ky == 1 && kx == 1) ? softplusf(c2[g]) : w2[g];
            }
        }
    }
    tab[e] = f2bf(v);
}

__global__ __launch_bounds__(256, 5) void fused_mfma(
    const float* __restrict__ x, const float* __restrict__ bias1,
    const float* __restrict__ res, const unsigned short* __restrict__ tab,
    float* __restrict__ out)
{
    __shared__ __align__(16) unsigned short xsb[XRow * XCol * 4];  // 3200 B
    __shared__ __align__(16) unsigned short hsb[NPX * 48];         // 29376 B

    const int tid  = threadIdx.x;
    const int b    = blockIdx.z;
    const int py0  = blockIdx.y * TS;
    const int px0  = blockIdx.x * TS;
    const int lane = tid & 63;
    const int wv   = tid >> 6;
    const int n    = lane & 15;
    const int q    = lane >> 4;

    // ---- stage x tile fp32->bf16 packed [r][c][4] ----
    const float* xb = x + b * NC * NH * NW;
    #pragma unroll
    for (int it = 0; it < 2; ++it) {
        unsigned p = tid + it * 256;
        if (p < XRow * XCol) {
            unsigned r = p / XCol, c = p - r * XCol;
            int gy = (int)(py0 - 2 + r), gx = (int)(px0 - 2 + c);
            bool ok = ((unsigned)gy < NH) && ((unsigned)gx < NW);
            const float* sp = xb + gy * NW + gx;
            float v0 = ok ? sp[0]           : 0.f;
            float v1 = ok ? sp[NH * NW]     : 0.f;
            float v2 = ok ? sp[2 * NH * NW] : 0.f;
            unsigned short s[4] = {rne(v0), rne(v1), rne(v2), 0};
            *(bf16x4*)(xsb + p * 4) = *(const bf16x4*)s;
        }
    }

    float rg; { float rv = res[0]; rg = rv > 0.f ? rv : 0.f; }
    // bias for channels f*16 + q*4 + r (r=0..3), f=0..2 -- 16B-aligned float4 loads
    float4 b4[3];
    #pragma unroll
    for (int f = 0; f < 3; ++f) b4[f] = *(const float4*)(bias1 + f * 16 + q * 4);

    // stage-1 A-frags (weights): coalesced 16B global loads (L2-hot table)
    bf16x8 a1f0 = *(const bf16x8*)(tab + (0 * 64 + lane) * 8);
    bf16x8 a1f1 = *(const bf16x8*)(tab + (1 * 64 + lane) * 8);
    bf16x8 a1f2 = *(const bf16x8*)(tab + (2 * 64 + lane) * 8);

    __syncthreads();  // xsb ready

    // ---- stage 1: 20 flat-px M-tiles, waves round-robin (5 each) ----
    #pragma unroll 1
    for (int t = wv; t < NT; t += 4) {
        unsigned p  = t * 16 + n;                 // this lane's pixel (B column)
        unsigned pr = p / 18, pc = p - pr * 18;
        const unsigned short* bp =
            xsb + ((pr + (q >> 1)) * XCol + pc + ((q & 1) << 1)) * 4;
        bf16x4 lo = *(const bf16x4*)bp;
        bf16x4 hi = *(const bf16x4*)(bp + 4);
        bf16x8 bf;
        #pragma unroll
        for (int j = 0; j < 4; ++j) { bf[j] = lo[j]; bf[4 + j] = hi[j]; }
        f32x4 z = {0.f, 0.f, 0.f, 0.f};
        f32x4 c0 = __builtin_amdgcn_mfma_f32_16x16x32_bf16(a1f0, bf, z, 0, 0, 0);
        f32x4 c1 = __builtin_amdgcn_mfma_f32_16x16x32_bf16(a1f1, bf, z, 0, 0, 0);
        f32x4 c2 = __builtin_amdgcn_mfma_f32_16x16x32_bf16(a1f2, bf, z, 0, 0, 0);
        // mask for this pixel (h row pr-1, col pc-1 in image coords)
        float mk = (((unsigned)(py0 + (int)pr - 1) < NH) &&
                    ((unsigned)(px0 + (int)pc - 1) < NW)) ? 1.f : 0.f;
        if (p < NPX) {
            unsigned short s0[4], s1[4], s2[4];
            #pragma unroll
            for (int r = 0; r < 4; ++r) {
                float v0 = c0[r] + ((const float*)&b4[0])[r];
                float v1 = c1[r] + ((const float*)&b4[1])[r];
                float v2 = c2[r] + ((const float*)&b4[2])[r];
                v0 = (v0 > 0.f ? v0 : __expf(v0) - 1.f) * mk;
                v1 = (v1 > 0.f ? v1 : __expf(v1) - 1.f) * mk;
                v2 = (v2 > 0.f ? v2 : __expf(v2) - 1.f) * mk;
                s0[r] = rne(v0); s1[r] = rne(v1); s2[r] = rne(v2);
            }
            unsigned short* hp = hsb + p * 48 + q * 4;
            *(bf16x4*)(hp +  0) = *(const bf16x4*)s0;   // ch  q*4..q*4+3
            *(bf16x4*)(hp + 16) = *(const bf16x4*)s1;   // ch 16+q*4..
            *(bf16x4*)(hp + 32) = *(const bf16x4*)s2;   // ch 32+q*4..
        }
    }

    // stage-2 B-frags (K-folded table): 8 coalesced 16B loads, before the barrier
    bf16x8 b2k[8];
    #pragma unroll
    for (int m = 0; m < 8; ++m)
        b2k[m] = *(const bf16x8*)(tab + W2OFF + (m * 64 + lane) * 8);

    // per-lane A-frag deltas (lane-constant across out rows)
    int dlt[8];
    #pragma unroll
    for (int m = 0; m < 8; ++m) {
        int idx = m * 32 + q * 8;            // k-octet start for this lane
        int c   = idx / 48;                  // combo (compile-folds to cheap seq)
        int off = idx - c * 48;              // channel octet within combo
        int ky  = (c >= 3) ? 1 : 0, kx = c - 3 * ky;
        dlt[m] = (idx < 240) ? ((ky * 18 + kx) * 48 + off) : 0;  // pad lanes: B cols zero
    }

    __syncthreads();  // hsb ready

    // ---- stage 2: out row py, K=240 folded in 8 MFMAs, 4 accumulators ----
    float* ob = out + b * NC * NH * NW;
    #pragma unroll 1
    for (int s = 0; s < 4; ++s) {
        int py = wv + s * 4;                 // out row 0..15
        const unsigned short* hbase = hsb + (py * 18 + n) * 48;
        f32x4 acc[4];
        #pragma unroll
        for (int a = 0; a < 4; ++a) acc[a] = (f32x4){0.f, 0.f, 0.f, 0.f};
        #pragma unroll
        for (int m = 0; m < 8; ++m) {
            bf16x8 af = *(const bf16x8*)(hbase + dlt[m]);
            acc[m & 3] = __builtin_amdgcn_mfma_f32_16x16x32_bf16(af, b2k[m], acc[m & 3], 0, 0, 0);
        }
        if (n < 3) {                          // lanes with a real out channel
            f32x4 t0, t1, sum;
            #pragma unroll
            for (int r = 0; r < 4; ++r) {
                t0[r] = acc[0][r] + acc[1][r];
                t1[r] = acc[2][r] + acc[3][r];
                sum[r] = t0[r] + t1[r];
            }
            int gy = py0 + py;
            const float* xp = xb + n * NH * NW + gy * NW + px0;
            float*       op = ob + n * NH * NW + gy * NW + px0;
            float4 xv = *(const float4*)(xp + q * 4);
            float4 o;
            o.x = sum[0] * (1.f / 16.f) + rg * xv.x;
            o.y = sum[1] * (1.f / 16.f) + rg * xv.y;
            o.z = sum[2] * (1.f / 16.f) + rg * xv.z;
            o.w = sum[3] * (1.f / 16.f) + rg * xv.w;
            *(float4*)(op + q * 4) = o;
        }
    }
}

extern "C" void kernel_launch(void* const* d_in, const int* in_sizes, int n_in,
                              void* d_out, int out_size, void* d_ws, size_t ws_size,
                              hipStream_t stream) {
    (void)in_sizes; (void)n_in; (void)out_size; (void)ws_size;
    const float* x   = (const float*)d_in[0];
    const float* w1  = (const float*)d_in[1];
    const float* c1  = (const float*)d_in[2];
    const float* b1  = (const float*)d_in[3];
    const float* w2  = (const float*)d_in[4];
    const float* c2  = (const float*)d_in[5];
    const float* res = (const float*)d_in[6];
    float* out = (float*)d_out;
    unsigned short* tab = (unsigned short*)d_ws;   // 11264 B of swizzled bf16 weights

    hipLaunchKernelGGL(prep_weights, dim3((WTN + 255) / 256), dim3(256), 0, stream,
                       w1, c1, w2, c2, tab);
    hipLaunchKernelGGL(fused_mfma, dim3(NW / TS, NH / TS, 64), dim3(256), 0, stream,
                       x, b1, res, tab, out);
}